// Round 1
// baseline (2417.814 us; speedup 1.0000x reference)
//
#include <hip/hip_runtime.h>
#include <stdint.h>

// ---------------------------------------------------------------------------
// HMM forward (MsaHmmCell): B=256 batches, T=512 steps, Q=1027 states, ALPHA=26
//
// Strategy: persistent kernel, 16 clusters x 16 WGs (grid=256, 256 thr/WG).
// Cluster c owns batches [16c,16c+16); WG j owns output cols [64j,64j+64)
// (WG15 also owns cols 1024..1026 via a k-split extra MFMA tile).
// Recurrence: u_t = E_t o (u_{t-1} @ A) / S_{t-1}, with S_{t-1} = sum(u_{t-1})
// exchanged one step late => exactly the reference normalization chain.
// A (softmaxed, bf16) lives in registers as MFMA B-fragments for all steps.
// Cross-WG exchange (g bf16 vectors, S partials, flags) uses sc0 sc1 memory
// ops (L2-bypassing, device-coherent) => correct for ANY WG->XCD placement.
// ---------------------------------------------------------------------------

#define Q     1027
#define TT    512
#define NBAT  256
#define ALPH  26
#define KH    1056          // padded K (33*32)
#define KCH   33            // k-chunks of 32
#define NTILE 65            // 16-col tiles covering 1040 >= 1027
#define ROWB  2128          // bytes per g row: 1064 bf16 (K pad +8 kills LDS bank conflicts)
#define GEXB  (16*ROWB)     // 34048 bytes per (cluster,parity) exchange image
#define NCL   16            // clusters
#define WPC   16            // workgroups per cluster
#define MB    16            // batches per cluster

typedef short  short8  __attribute__((ext_vector_type(8)));
typedef float  floatx4 __attribute__((ext_vector_type(4)));
typedef int    intx4   __attribute__((ext_vector_type(4)));

static constexpr size_t al512(size_t x) { return (x + 511) & ~size_t(511); }
static constexpr size_t OFF_APACK = 0;
static constexpr size_t SZ_APACK  = (size_t)NTILE * KCH * 64 * 16;      // 2,196,480
static constexpr size_t OFF_BSOFT = al512(OFF_APACK + SZ_APACK);
static constexpr size_t SZ_BSOFT  = (size_t)Q * ALPH * 4;
static constexpr size_t OFF_INIT  = al512(OFF_BSOFT + SZ_BSOFT);
static constexpr size_t OFF_AMAX  = al512(OFF_INIT + Q * 4);
static constexpr size_t OFF_AINV  = al512(OFF_AMAX + Q * 4);
static constexpr size_t OFF_GEX   = al512(OFF_AINV + Q * 4);
static constexpr size_t SZ_GEX    = (size_t)NCL * 2 * GEXB + 1024;      // + overrun pad
static constexpr size_t OFF_FLAGS = al512(OFF_GEX + SZ_GEX);
static constexpr size_t SZ_FLAGS  = (size_t)NCL * WPC * 4;
static constexpr size_t OFF_SPART = al512(OFF_FLAGS + SZ_FLAGS);
static constexpr size_t SZ_SPART  = (size_t)NCL * 2 * WPC * MB * 4;
static constexpr size_t WS_NEED   = OFF_SPART + SZ_SPART;
static constexpr size_t FWDSZ     = (size_t)NBAT * TT * Q;              // 134,610,944

__device__ __forceinline__ uint32_t f2bf(float f) {
  uint32_t u = __float_as_uint(f);
  return (u + 0x7fffu + ((u >> 16) & 1u)) >> 16;   // RNE, no NaN inputs here
}

// ------------------------- prep kernels ------------------------------------

__global__ void k_zero(char* __restrict__ ws) {
  const size_t n = (WS_NEED - OFF_GEX) / 16;
  intx4* p = (intx4*)(ws + OFF_GEX);
  for (size_t i = (size_t)blockIdx.x * 256 + threadIdx.x; i < n; i += (size_t)275 * 256)
    p[i] = intx4{0, 0, 0, 0};
}

__global__ void k_astats(const float* __restrict__ A, char* __restrict__ ws) {
  const int r = blockIdx.x, tid = threadIdx.x;
  const float* row = A + (size_t)r * Q;
  __shared__ float red[4], red2[4];
  float mx = -3.0e38f;
  for (int i = tid; i < Q; i += 256) mx = fmaxf(mx, row[i]);
#pragma unroll
  for (int d = 1; d < 64; d <<= 1) mx = fmaxf(mx, __shfl_xor(mx, d));
  if ((tid & 63) == 0) red[tid >> 6] = mx;
  __syncthreads();
  mx = fmaxf(fmaxf(red[0], red[1]), fmaxf(red[2], red[3]));
  float s = 0.f;
  for (int i = tid; i < Q; i += 256) s += expf(row[i] - mx);
#pragma unroll
  for (int d = 1; d < 64; d <<= 1) s += __shfl_xor(s, d);
  if ((tid & 63) == 0) red2[tid >> 6] = s;
  __syncthreads();
  s = red2[0] + red2[1] + red2[2] + red2[3];
  if (tid == 0) {
    *(float*)(ws + OFF_AMAX + (size_t)r * 4) = mx;
    *(float*)(ws + OFF_AINV + (size_t)r * 4) = 1.0f / s;
  }
}

__global__ void k_bsoft(const float* __restrict__ Bl, char* __restrict__ ws) {
  const int r = blockIdx.x, l = threadIdx.x;  // 64 threads
  float v = (l < ALPH) ? Bl[(size_t)r * ALPH + l] : -3.0e38f;
  float mx = v;
#pragma unroll
  for (int d = 1; d < 64; d <<= 1) mx = fmaxf(mx, __shfl_xor(mx, d));
  float e = (l < ALPH) ? expf(v - mx) : 0.f;
  float s = e;
#pragma unroll
  for (int d = 1; d < 64; d <<= 1) s += __shfl_xor(s, d);
  if (l < ALPH) *(float*)(ws + OFF_BSOFT + ((size_t)r * ALPH + l) * 4) = e / s;
}

__global__ void k_isoft(const float* __restrict__ il, char* __restrict__ ws) {
  const int tid = threadIdx.x;
  __shared__ float red[4], red2[4];
  float mx = -3.0e38f;
  for (int i = tid; i < Q; i += 256) mx = fmaxf(mx, il[i]);
#pragma unroll
  for (int d = 1; d < 64; d <<= 1) mx = fmaxf(mx, __shfl_xor(mx, d));
  if ((tid & 63) == 0) red[tid >> 6] = mx;
  __syncthreads();
  mx = fmaxf(fmaxf(red[0], red[1]), fmaxf(red[2], red[3]));
  float s = 0.f;
  for (int i = tid; i < Q; i += 256) s += expf(il[i] - mx);
#pragma unroll
  for (int d = 1; d < 64; d <<= 1) s += __shfl_xor(s, d);
  if ((tid & 63) == 0) red2[tid >> 6] = s;
  __syncthreads();
  s = red2[0] + red2[1] + red2[2] + red2[3];
  const float inv = 1.0f / s;
  for (int i = tid; i < Q; i += 256)
    *(float*)(ws + OFF_INIT + (size_t)i * 4) = expf(il[i] - mx) * inv;
}

// Repack softmax(A) into MFMA B-operand fragment layout:
// Apack[ntile][kc][lane][e]  =  A[k = kc*32 + (lane>>4)*8 + e][q = ntile*16 + (lane&15)]
__global__ void k_repack(const float* __restrict__ A, char* __restrict__ ws) {
  const int b = blockIdx.x;
  const int nt = b % NTILE, kc = b / NTILE;
  const int lane = threadIdx.x;
  const int q = nt * 16 + (lane & 15);
  const int kb = kc * 32 + (lane >> 4) * 8;
  union { short8 v; unsigned short u[8]; } pk;
#pragma unroll
  for (int e = 0; e < 8; ++e) {
    const int k = kb + e;
    float val = 0.f;
    if (k < Q && q < Q) {
      const float mxk = *(const float*)(ws + OFF_AMAX + (size_t)k * 4);
      const float ivk = *(const float*)(ws + OFF_AINV + (size_t)k * 4);
      val = expf(A[(size_t)k * Q + q] - mxk) * ivk;
    }
    pk.u[e] = (unsigned short)f2bf(val);
  }
  *(short8*)(ws + OFF_APACK + (((size_t)nt * KCH + kc) * 64 + lane) * 16) = pk.v;
}

// ------------------------- main persistent kernel --------------------------

__global__ __launch_bounds__(256) void k_main(const int* __restrict__ xin,
                                              char* __restrict__ ws,
                                              float* __restrict__ out) {
  const int bid = blockIdx.x;
  const int c = bid & 15, j = bid >> 4;
  const int tid = threadIdx.x;
  const int lane = tid & 63, w = tid >> 6;
  const int cL = lane & 15, g4 = lane >> 4;
  const bool j15 = (j == 15), two = (j15 && w == 3);
  const int t0 = 4 * j + w;
  const int col0 = t0 * 16;
  const int ntl = j15 ? 5 : 4;
  const uint64_t wsu = (uint64_t)(uintptr_t)ws;

  __shared__ intx4   g_lds4[2176 + 16];
  __shared__ uint8_t x_lds[MB * TT];
  __shared__ float   B_lds[5][16][ALPH];
  __shared__ float   init_lds[5][16];
  __shared__ float   Sp_lds[4][16];
  __shared__ float   accx_lds[4][64][4];

  // ---- stage per-WG constants ----
  for (int idx = tid; idx < MB * TT; idx += 256)
    x_lds[idx] = (uint8_t)xin[(size_t)(c * MB) * TT + idx];
  for (int idx = tid; idx < ntl * 16 * ALPH; idx += 256) {
    const int tl = idx / (16 * ALPH), rem = idx % (16 * ALPH);
    const int cc = rem / ALPH, a = rem % ALPH;
    const int grow = (tl < 4 ? 64 * j + tl * 16 : 1024) + cc;
    B_lds[tl][cc][a] = (grow < Q) ? *(const float*)(ws + OFF_BSOFT + ((size_t)grow * ALPH + a) * 4) : 0.f;
  }
  for (int idx = tid; idx < ntl * 16; idx += 256) {
    const int tl = idx / 16, cc = idx % 16;
    const int grow = (tl < 4 ? 64 * j + tl * 16 : 1024) + cc;
    init_lds[tl][cc] = (grow < Q) ? *(const float*)(ws + OFF_INIT + (size_t)grow * 4) : 0.f;
  }

  // ---- persistent A fragments (registers) ----
  short8 af0[KCH];
#pragma unroll
  for (int kc = 0; kc < KCH; ++kc)
    af0[kc] = *(const short8*)(ws + OFF_APACK + (((size_t)t0 * KCH + kc) * 64 + lane) * 16);
  short8 af64[9];
  if (j15) {
#pragma unroll
    for (int i = 0; i < 9; ++i) {
      if (i < 8 || w == 3) {
        const int kc = w * 8 + i;
        af64[i] = *(const short8*)(ws + OFF_APACK + (((size_t)64 * KCH + kc) * 64 + lane) * 16);
      }
    }
  }
  __syncthreads();

  float up0[4], up1[4] = {0.f, 0.f, 0.f, 0.f};

  // ---- step 0: u0 = E0 * init ----
#pragma unroll
  for (int r = 0; r < 4; ++r) {
    const int m = g4 * 4 + r;
    const int xm = x_lds[m * TT + 0];
    up0[r] = B_lds[w][cL][xm] * init_lds[w][cL];
    if (two) up1[r] = B_lds[4][cL][xm] * init_lds[4][cL];
  }

  // publish step tcur: exchange bf16 tile + per-WG S partials + flag(tcur+1)
#define POST_STEP(TCUR)                                                                   \
  do {                                                                                    \
    const int par_ = (TCUR) & 1;                                                          \
    const uint64_t gb_ = wsu + OFF_GEX + (size_t)(c * 2 + par_) * GEXB;                   \
    float tmp_[4];                                                                        \
    _Pragma("unroll") for (int r = 0; r < 4; ++r) {                                       \
      const int m_ = g4 * 4 + r;                                                          \
      uint32_t b0_ = f2bf(up0[r]);                                                        \
      asm volatile("global_store_short %0, %1, off sc0 sc1" ::                            \
                   "v"(gb_ + (size_t)m_ * ROWB + (size_t)(col0 + cL) * 2), "v"(b0_)       \
                   : "memory");                                                           \
      tmp_[r] = up0[r];                                                                   \
      if (two) {                                                                          \
        uint32_t b1_ = f2bf(up1[r]);                                                      \
        asm volatile("global_store_short %0, %1, off sc0 sc1" ::                          \
                     "v"(gb_ + (size_t)m_ * ROWB + (size_t)(1024 + cL) * 2), "v"(b1_)     \
                     : "memory");                                                         \
        tmp_[r] += up1[r];                                                                \
      }                                                                                   \
    }                                                                                     \
    _Pragma("unroll") for (int r = 0; r < 4; ++r) {                                       \
      _Pragma("unroll") for (int d = 1; d < 16; d <<= 1) tmp_[r] += __shfl_xor(tmp_[r], d); \
    }                                                                                     \
    if (cL == 0) {                                                                        \
      _Pragma("unroll") for (int r = 0; r < 4; ++r) Sp_lds[w][g4 * 4 + r] = tmp_[r];      \
    }                                                                                     \
    asm volatile("s_waitcnt vmcnt(0)" ::: "memory");                                      \
    __syncthreads();                                                                      \
    if (w == 0) {                                                                         \
      if (lane < 16) {                                                                    \
        float sw_ = Sp_lds[0][lane] + Sp_lds[1][lane] + Sp_lds[2][lane] + Sp_lds[3][lane];\
        uint64_t sa_ = wsu + OFF_SPART + (size_t)(((c * 2 + par_) * WPC + j) * MB + lane) * 4; \
        asm volatile("global_store_dword %0, %1, off sc0 sc1\n\ts_waitcnt vmcnt(0)" ::    \
                     "v"(sa_), "v"(sw_) : "memory");                                      \
      }                                                                                   \
      if (lane == 0) {                                                                    \
        uint64_t fa_ = wsu + OFF_FLAGS + (size_t)(c * WPC + j) * 4;                       \
        int fv_ = (TCUR) + 1;                                                             \
        asm volatile("global_store_dword %0, %1, off sc0 sc1" :: "v"(fa_), "v"(fv_)       \
                     : "memory");                                                         \
      }                                                                                   \
    }                                                                                     \
  } while (0)

  // wait until all 16 WGs of the cluster posted flag >= TGT
#define WAIT_FLAGS(TGT)                                                                   \
  do {                                                                                    \
    if (w == 0) {                                                                         \
      const uint64_t fa_ = wsu + OFF_FLAGS + (size_t)(c * WPC + cL) * 4;                  \
      for (;;) {                                                                          \
        int f_;                                                                           \
        asm volatile("global_load_dword %0, %1, off sc0 sc1\n\ts_waitcnt vmcnt(0)"        \
                     : "=v"(f_) : "v"(fa_) : "memory");                                   \
        if (__all(f_ >= (TGT))) break;                                                    \
        __builtin_amdgcn_s_sleep(2);                                                      \
      }                                                                                   \
    }                                                                                     \
    __syncthreads();                                                                      \
  } while (0)

  // load 16 WG-partials for parity PARP, produce s (=S[m=cL] in every lane)
#define SPART_BLOCK(PARP, SVAR)                                                           \
  float SVAR;                                                                             \
  do {                                                                                    \
    const uint64_t sb_ = wsu + OFF_SPART + (size_t)((c * 2 + (PARP)) * WPC) * MB * 4;     \
    float p0_, p1_, p2_, p3_;                                                             \
    uint64_t a0_ = sb_ + (size_t)((g4 + 0) * MB + cL) * 4;                                \
    uint64_t a1_ = sb_ + (size_t)((g4 + 4) * MB + cL) * 4;                                \
    uint64_t a2_ = sb_ + (size_t)((g4 + 8) * MB + cL) * 4;                                \
    uint64_t a3_ = sb_ + (size_t)((g4 + 12) * MB + cL) * 4;                               \
    asm volatile("global_load_dword %0, %4, off sc0 sc1\n\t"                              \
                 "global_load_dword %1, %5, off sc0 sc1\n\t"                              \
                 "global_load_dword %2, %6, off sc0 sc1\n\t"                              \
                 "global_load_dword %3, %7, off sc0 sc1\n\t"                              \
                 "s_waitcnt vmcnt(0)"                                                     \
                 : "=v"(p0_), "=v"(p1_), "=v"(p2_), "=v"(p3_)                             \
                 : "v"(a0_), "v"(a1_), "v"(a2_), "v"(a3_) : "memory");                    \
    SVAR = p0_ + p1_ + p2_ + p3_;                                                         \
    SVAR += __shfl_xor(SVAR, 16);                                                         \
    SVAR += __shfl_xor(SVAR, 32);                                                         \
  } while (0)

  POST_STEP(0);

  float llacc = 0.f;

  for (int t = 1; t < TT; ++t) {
    const int parp = (t - 1) & 1;

    WAIT_FLAGS(t);

    // issue staging loads of g_{t-1} (L3-coherent)
    const uint64_t gbp = wsu + OFF_GEX + (size_t)(c * 2 + parp) * GEXB;
    intx4 sgv[9];
#pragma unroll
    for (int i = 0; i < 8; ++i) {
      uint64_t a = gbp + (size_t)((i * 256 + tid) * 16);
      asm volatile("global_load_dwordx4 %0, %1, off sc0 sc1" : "=v"(sgv[i]) : "v"(a) : "memory");
    }
    const bool has9 = (tid < 80);  // 2128 = 8*256 + 80 int4s
    if (has9) {
      uint64_t a = gbp + (size_t)((2048 + tid) * 16);
      asm volatile("global_load_dwordx4 %0, %1, off sc0 sc1" : "=v"(sgv[8]) : "v"(a) : "memory");
    }

    SPART_BLOCK(parp, s);  // also drains the staging loads (vmcnt 0)

    // write staged g into LDS
#pragma unroll
    for (int i = 0; i < 8; ++i) g_lds4[i * 256 + tid] = sgv[i];
    if (has9) g_lds4[2048 + tid] = sgv[8];

    if (j == 0 && w == 0) llacc += logf(s);
    float invS[4];
#pragma unroll
    for (int r = 0; r < 4; ++r) invS[r] = 1.0f / __shfl(s, g4 * 4 + r);

    // forward output for step t-1 (normalized now that S_{t-1} is known)
#pragma unroll
    for (int r = 0; r < 4; ++r) {
      const int m = g4 * 4 + r;
      const size_t ob = ((size_t)(c * MB + m) * TT + (t - 1)) * Q;
      __builtin_nontemporal_store(up0[r] * invS[r], out + ob + col0 + cL);
      if (two && cL < 3)
        __builtin_nontemporal_store(up1[r] * invS[r], out + ob + 1024 + cL);
    }
    __syncthreads();  // g_lds ready

    // matvec: r = g_{t-1} @ A  (per-wave 16x16 tile, K = 1056)
    floatx4 a0v = {0, 0, 0, 0}, a1v = {0, 0, 0, 0}, a64v = {0, 0, 0, 0};
    const char* gl = (const char*)g_lds4;
    const int gof = cL * ROWB + g4 * 16;
#pragma unroll
    for (int kc = 0; kc < KCH; ++kc) {
      short8 gf = *(const short8*)(gl + gof + kc * 64);
      if (kc & 1) a1v = __builtin_amdgcn_mfma_f32_16x16x32_bf16(gf, af0[kc], a1v, 0, 0, 0);
      else        a0v = __builtin_amdgcn_mfma_f32_16x16x32_bf16(gf, af0[kc], a0v, 0, 0, 0);
    }
    float r1v[4];
    if (j15) {  // extra tile (cols 1024..1039): k-split across the 4 waves
#pragma unroll
      for (int i = 0; i < 9; ++i) {
        if (i < 8 || w == 3) {
          const int kc = w * 8 + i;
          short8 gf = *(const short8*)(gl + gof + kc * 64);
          a64v = __builtin_amdgcn_mfma_f32_16x16x32_bf16(gf, af64[i], a64v, 0, 0, 0);
        }
      }
#pragma unroll
      for (int r = 0; r < 4; ++r) accx_lds[w][lane][r] = a64v[r];
      __syncthreads();
      if (two) {
#pragma unroll
        for (int r = 0; r < 4; ++r)
          r1v[r] = accx_lds[0][lane][r] + accx_lds[1][lane][r] +
                   accx_lds[2][lane][r] + accx_lds[3][lane][r];
      }
    }

    // epilogue: u_t = E_t * r * (1/S_{t-1})
#pragma unroll
    for (int r = 0; r < 4; ++r) {
      const int m = g4 * 4 + r;
      const int xm = x_lds[m * TT + t];
      up0[r] = (a0v[r] + a1v[r]) * B_lds[w][cL][xm] * invS[r];
      if (two) up1[r] = r1v[r] * B_lds[4][cL][xm] * invS[r];
    }

    POST_STEP(t);
  }

  // ---- final: S_511, output t=511, loglik ----
  WAIT_FLAGS(TT);
  {
    SPART_BLOCK((TT - 1) & 1, s);
    if (j == 0 && w == 0) llacc += logf(s);
    float invS[4];
#pragma unroll
    for (int r = 0; r < 4; ++r) invS[r] = 1.0f / __shfl(s, g4 * 4 + r);
#pragma unroll
    for (int r = 0; r < 4; ++r) {
      const int m = g4 * 4 + r;
      const size_t ob = ((size_t)(c * MB + m) * TT + (TT - 1)) * Q;
      __builtin_nontemporal_store(up0[r] * invS[r], out + ob + col0 + cL);
      if (two && cL < 3)
        __builtin_nontemporal_store(up1[r] * invS[r], out + ob + 1024 + cL);
    }
    if (j == 0 && w == 0 && lane < 16) out[FWDSZ + (size_t)c * MB + lane] = llacc;
  }
}

// ------------------------- launch ------------------------------------------

extern "C" void kernel_launch(void* const* d_in, const int* in_sizes, int n_in,
                              void* d_out, int out_size, void* d_ws, size_t ws_size,
                              hipStream_t stream) {
  const int*   x    = (const int*)d_in[0];
  const float* Alog = (const float*)d_in[1];
  const float* Blog = (const float*)d_in[2];
  const float* ilog = (const float*)d_in[3];
  char*  ws  = (char*)d_ws;
  float* out = (float*)d_out;
  if (ws_size < WS_NEED) return;  // defensive: need ~3.3 MB scratch

  hipLaunchKernelGGL(k_zero,   dim3(275),         dim3(256), 0, stream, ws);
  hipLaunchKernelGGL(k_astats, dim3(Q),           dim3(256), 0, stream, Alog, ws);
  hipLaunchKernelGGL(k_bsoft,  dim3(Q),           dim3(64),  0, stream, Blog, ws);
  hipLaunchKernelGGL(k_isoft,  dim3(1),           dim3(256), 0, stream, ilog, ws);
  hipLaunchKernelGGL(k_repack, dim3(NTILE * KCH), dim3(64),  0, stream, Alog, ws);
  hipLaunchKernelGGL(k_main,   dim3(256),         dim3(256), 0, stream, x, ws, out);
}